// Round 1
// baseline (176.706 us; speedup 1.0000x reference)
//
#include <hip/hip_runtime.h>
#include <hip/hip_fp16.h>

// SparseLinear: out[NR,128] = segment_sum(vals[i] * W[cols[i],:], rows[i]) + b
// R8: occupancy-first restructure.
//  - 98-row buckets (magic-div, non-pow2) -> nbc=1021 blocks ~= 1024 wg slots
//    (512-thr blocks, 4 blocks/CU) -> ~100% grid fill, no half-idle CUs.
//  - fused: 512 threads, ~21 KB LDS, launch_bounds(512,8) -> 32 waves/CU;
//    bucket staged via registers (single global read of A).
//  - partition: direct scatter, LDS = 4 KB hist only, rows held in regs;
//    no scan / no inverse-rank sort (L2 merges the 8B bucket writes).

#define UNITS 128
#define SCAN_BLK 1024
#define BROW 98          // rows per bucket (non-pow2 for grid fill)
#define NBC_PAD 1040     // padded bucket-count capacity (actual 1021)
#define BCAP 2528        // fixed bucket capacity (mean 1960, +12.8 sigma)
#define CH2 8192         // partition chunk per block (512 thr * 16)
#define SPILL_CAP 8192

// ---------- setup: cursors + spill counter + W fp32->fp16 ----------

__global__ __launch_bounds__(256) void setup_kernel(
        const float* __restrict__ W, __half2* __restrict__ Wh,
        int* __restrict__ ccur, int* __restrict__ spill_cnt,
        int nbc, int wn2 /* = 8192*128/2 half2 elements */) {
    int t = blockIdx.x * blockDim.x + threadIdx.x;
    if (t < nbc) ccur[t] = t * BCAP;
    if (t == nbc) *spill_cnt = 0;
    int stride = gridDim.x * blockDim.x;
    const float2* W2 = (const float2*)W;
    for (int i = t; i < wn2; i += stride)
        Wh[i] = __float22half2_rn(W2[i]);
}

// ---------- phase A: direct-scatter partition by row/98 ----------

__global__ __launch_bounds__(512, 6) void partition_kernel(
        const float* __restrict__ vals, const int* __restrict__ rows,
        const int* __restrict__ cols, int* __restrict__ ccur,
        float2* __restrict__ sortedA, int* __restrict__ spill_cnt,
        float2* __restrict__ spill, int nnz, int nbc) {
    __shared__ int hist[NBC_PAD];              // 4 KB only -> wave-capped occ

    const int t = threadIdx.x;                 // 512 threads
    const int chunk0 = blockIdx.x * CH2;

    for (int s = t; s < NBC_PAD; s += 512) hist[s] = 0;
    __syncthreads();

    // pass 1: histogram (rows cached in registers)
    int rbuf[16];
#pragma unroll
    for (int j = 0; j < 16; ++j) {
        int i = chunk0 + j * 512 + t;
        int row = (i < nnz) ? rows[i] : -1;
        rbuf[j] = row;
        if (row >= 0) atomicAdd(&hist[row / BROW], 1);
    }
    __syncthreads();

    // reserve global segments; hist becomes the scatter cursor
    for (int s = t; s < nbc; s += 512) {
        int c = hist[s];
        int g = (c > 0) ? atomicAdd(&ccur[s], c) : 0;
        hist[s] = g;                           // each s owned by one thread
    }
    __syncthreads();

    // pass 2: direct scatter (L2 merges the 8B writes within segments)
#pragma unroll
    for (int j = 0; j < 16; ++j) {
        int row = rbuf[j];
        if (row < 0) continue;
        int i = chunk0 + j * 512 + t;
        int bkt = row / BROW;
        int rowlo = row - bkt * BROW;
        int dest = atomicAdd(&hist[bkt], 1);
        float v = vals[i];
        int col = cols[i];
        if (dest < (bkt + 1) * BCAP) {
            sortedA[dest] = make_float2(v, __int_as_float(col | (rowlo << 13)));
        } else {
            int sp = atomicAdd(spill_cnt, 1);
            if (sp < SPILL_CAP)
                spill[sp] = make_float2(v, __int_as_float(col | (row << 13)));
        }
    }
}

// ---------- phase B (fused): in-LDS row sort + register accumulate ----------

__global__ __launch_bounds__(512, 8) void fused_sort_compute_kernel(
        const float2* __restrict__ A, const int* __restrict__ ccur,
        const __half2* __restrict__ Wh, const float* __restrict__ b,
        float* __restrict__ out, const int* __restrict__ spill_cnt,
        const float2* __restrict__ spill, int NR) {
    __shared__ float2 st[BCAP + 8];   // ~20.3 KB sorted (val,col) pairs
    __shared__ int cnt_s[128];        // counts -> scatter cursor
    __shared__ int rs[132];           // stable local row starts
    __shared__ int spill_n;
    const int t = threadIdx.x;        // 512 threads = 8 waves
    const int lane = t & 63;
    const int w = t >> 6;
    const int bb = blockIdx.x;
    const int r0 = bb * BROW;
    const int gstart = bb * BCAP;
    int cnt = ccur[bb] - gstart;
    if (cnt > BCAP) cnt = BCAP;       // overflow entries are in the spill list

    const float2 bias = ((const float2*)b)[lane];

    if (t < 128) cnt_s[t] = 0;
    if (t == 0) {
        int sn = *spill_cnt;
        spill_n = (sn > SPILL_CAP) ? SPILL_CAP : sn;
    }
    __syncthreads();

    // pass 1: single global read of the bucket into registers + histogram
    float2 e[5];
#pragma unroll
    for (int j = 0; j < 5; ++j) {
        int k = j * 512 + t;
        if (k < cnt) {
            e[j] = A[gstart + k];
            atomicAdd(&cnt_s[(__float_as_int(e[j].y) >> 13) & 127], 1);
        }
    }
    __syncthreads();

    // exclusive scan over 128 counts
    if (t < 128) rs[t] = cnt_s[t];
    __syncthreads();
    for (int off = 1; off < 128; off <<= 1) {
        int v = (t < 128 && t >= off) ? rs[t - off] : 0;
        __syncthreads();
        if (t < 128) rs[t] += v;
        __syncthreads();
    }
    int excl = (t < 128) ? rs[t] - cnt_s[t] : 0;
    __syncthreads();
    if (t < 128) { rs[t] = excl; cnt_s[t] = excl; }
    if (t == 0) rs[128] = cnt;
    __syncthreads();

    // pass 2: scatter from registers into LDS in exact row order
#pragma unroll
    for (int j = 0; j < 5; ++j) {
        int k = j * 512 + t;
        if (k < cnt) {
            int pk = __float_as_int(e[j].y);
            int p = atomicAdd(&cnt_s[(pk >> 13) & 127], 1);
            st[p] = make_float2(e[j].x, __int_as_float(pk & 8191));
        }
    }
    __syncthreads();

    // compute: wave w -> rows {w, w+8, ...}, register accumulation,
    // fp16 W gathers (L2-resident 2MB table)
    const int sn = spill_n;
    for (int r = w; r < BROW; r += 8) {
        int grow = r0 + r;
        if (grow >= NR) break;        // r increases with wave-uniform stride
        int s = rs[r], ee = rs[r + 1];
        float ax0 = 0.f, ay0 = 0.f, ax1 = 0.f, ay1 = 0.f;
        for (int k = s; k < ee; k += 4) {
            float2 p0 = st[k];
            float2 p1 = st[k + 1];
            float2 p2 = st[k + 2];
            float2 p3 = st[k + 3];
            int c0 = __float_as_int(p0.y) & 8191;
            int c1 = __float_as_int(p1.y) & 8191;
            int c2 = __float_as_int(p2.y) & 8191;
            int c3 = __float_as_int(p3.y) & 8191;
            float v0 = p0.x;
            float v1 = (k + 1 < ee) ? p1.x : 0.f;
            float v2 = (k + 2 < ee) ? p2.x : 0.f;
            float v3 = (k + 3 < ee) ? p3.x : 0.f;
            float2 w0 = __half22float2(Wh[c0 * 64 + lane]);  // 4 independent L2 gathers
            float2 w1 = __half22float2(Wh[c1 * 64 + lane]);
            float2 w2 = __half22float2(Wh[c2 * 64 + lane]);
            float2 w3 = __half22float2(Wh[c3 * 64 + lane]);
            ax0 += v0 * w0.x; ay0 += v0 * w0.y;
            ax1 += v1 * w1.x; ay1 += v1 * w1.y;
            ax0 += v2 * w2.x; ay0 += v2 * w2.y;
            ax1 += v3 * w3.x; ay1 += v3 * w3.y;
        }
        // spill entries (normally sn == 0)
        for (int s2 = 0; s2 < sn; ++s2) {
            float2 es = spill[s2];
            int pk = __float_as_int(es.y);
            if ((pk >> 13) == grow) {
                float2 wv = __half22float2(Wh[(pk & 8191) * 64 + lane]);
                ax0 += es.x * wv.x; ay0 += es.x * wv.y;
            }
        }
        ((float2*)out)[(size_t)grow * 64 + lane] =
            make_float2(ax0 + ax1 + bias.x, ay0 + ay1 + bias.y);
    }
}

// ---------- tier-2 fallback kernels (R2 pipeline, fp32 W) ----------

__global__ void hist_kernel(const int* __restrict__ rows, int* __restrict__ counts, int nnz) {
    int i = blockIdx.x * blockDim.x + threadIdx.x;
    if (i < nnz) atomicAdd(&counts[rows[i]], 1);
}

__global__ void scan1_kernel(const int* __restrict__ counts, int* __restrict__ tmp,
                             int* __restrict__ bsums, int NR, int NS) {
    __shared__ int s[SCAN_BLK];
    int t = threadIdx.x;
    int i = blockIdx.x * SCAN_BLK + t;
    int x = (i < NR) ? counts[i] : 0;
    s[t] = x;
    __syncthreads();
    for (int off = 1; off < SCAN_BLK; off <<= 1) {
        int v = (t >= off) ? s[t - off] : 0;
        __syncthreads();
        s[t] += v;
        __syncthreads();
    }
    if (i < NS) tmp[i] = s[t] - x;
    if (t == SCAN_BLK - 1) bsums[blockIdx.x] = s[SCAN_BLK - 1];
}

__global__ void scan2_kernel(int* __restrict__ bsums, int nb) {
    if (threadIdx.x == 0 && blockIdx.x == 0) {
        int run = 0;
        for (int i = 0; i < nb; ++i) { int c = bsums[i]; bsums[i] = run; run += c; }
    }
}

__global__ void scan3_kernel(const int* __restrict__ tmp, const int* __restrict__ bsums,
                             int* __restrict__ row_start, int* __restrict__ cursor,
                             int NR, int NS) {
    int i = blockIdx.x * blockDim.x + threadIdx.x;
    if (i < NS) {
        int v = tmp[i] + bsums[i >> 10];
        row_start[i] = v;
        if (i < NR) cursor[i] = v;
    }
}

__global__ void scatter_sort_kernel(const float* __restrict__ vals, const int* __restrict__ rows,
                                    const int* __restrict__ cols, int* __restrict__ cursor,
                                    float2* __restrict__ sorted, int nnz) {
    int i = blockIdx.x * blockDim.x + threadIdx.x;
    if (i < nnz) {
        int r = rows[i];
        int p = atomicAdd(&cursor[r], 1);
        sorted[p] = make_float2(vals[i], __int_as_float(cols[i]));
    }
}

__global__ void compute_kernel(const float2* __restrict__ sorted, const int* __restrict__ row_start,
                               const float* __restrict__ W, const float* __restrict__ b,
                               float* __restrict__ out, int NR) {
    int lane = threadIdx.x & 63;
    int wv = threadIdx.x >> 6;
    int row = blockIdx.x * 4 + wv;
    if (row >= NR) return;
    int start = row_start[row];
    int end   = row_start[row + 1];
    const float2* W2 = (const float2*)W;
    float accx0 = 0.f, accy0 = 0.f, accx1 = 0.f, accy1 = 0.f;
    for (int base = start; base < end; base += 64) {
        int m = end - base;
        if (m > 64) m = 64;
        float2 p = make_float2(0.f, __int_as_float(0));
        if (lane < m) p = sorted[base + lane];
        int vi = __float_as_int(p.x);
        int ci = __float_as_int(p.y);
        int rounds = (m + 3) & ~3;
        for (int j = 0; j < rounds; j += 4) {
            float v0 = __int_as_float(__builtin_amdgcn_readlane(vi, j));
            int   c0 = __builtin_amdgcn_readlane(ci, j);
            float v1 = __int_as_float(__builtin_amdgcn_readlane(vi, j + 1));
            int   c1 = __builtin_amdgcn_readlane(ci, j + 1);
            float v2 = __int_as_float(__builtin_amdgcn_readlane(vi, j + 2));
            int   c2 = __builtin_amdgcn_readlane(ci, j + 2);
            float v3 = __int_as_float(__builtin_amdgcn_readlane(vi, j + 3));
            int   c3 = __builtin_amdgcn_readlane(ci, j + 3);
            float2 w0 = W2[c0 * 64 + lane];
            float2 w1 = W2[c1 * 64 + lane];
            float2 w2 = W2[c2 * 64 + lane];
            float2 w3 = W2[c3 * 64 + lane];
            accx0 += v0 * w0.x; accy0 += v0 * w0.y;
            accx1 += v1 * w1.x; accy1 += v1 * w1.y;
            accx0 += v2 * w2.x; accy0 += v2 * w2.y;
            accx1 += v3 * w3.x; accy1 += v3 * w3.y;
        }
    }
    float2 bb = ((const float2*)b)[lane];
    ((float2*)out)[(size_t)row * 64 + lane] =
        make_float2(accx0 + accx1 + bb.x, accy0 + accy1 + bb.y);
}

// ---------- tier-3 fallback (atomic path) ----------

__global__ void init_bias_kernel(float* __restrict__ out, const float* __restrict__ b, int total4) {
    const float4* b4 = (const float4*)b;
    float4* out4 = (float4*)out;
    int stride = gridDim.x * blockDim.x;
    for (int j = blockIdx.x * blockDim.x + threadIdx.x; j < total4; j += stride)
        out4[j] = b4[j & 31];
}

__global__ void scatter_atomic_kernel(const float* __restrict__ vals, const int* __restrict__ rows,
                                      const int* __restrict__ cols, const float* __restrict__ W,
                                      float* __restrict__ out, int nnz) {
    long long idx = (long long)blockIdx.x * blockDim.x + threadIdx.x;
    int i = (int)(idx >> 5);
    int c = (int)(idx & 31);
    if (i >= nnz) return;
    int row = rows[i], col = cols[i];
    float v = vals[i];
    float4 w = ((const float4*)W)[col * 32 + c];
    float* o = out + (size_t)row * UNITS + (c << 2);
    atomicAdd(o + 0, v * w.x);
    atomicAdd(o + 1, v * w.y);
    atomicAdd(o + 2, v * w.z);
    atomicAdd(o + 3, v * w.w);
}

extern "C" void kernel_launch(void* const* d_in, const int* in_sizes, int n_in,
                              void* d_out, int out_size, void* d_ws, size_t ws_size,
                              hipStream_t stream) {
    const float* vals = (const float*)d_in[0];
    const int*   rows = (const int*)d_in[1];
    const int*   cols = (const int*)d_in[2];
    const float* W    = (const float*)d_in[3];
    const float* b    = (const float*)d_in[4];
    float* out = (float*)d_out;

    const int nnz = in_sizes[0];
    const int NW  = in_sizes[3];            // 8192*128
    const int NR  = out_size / UNITS;
    const int NS  = NR + 1;
    const int NB  = (NS + SCAN_BLK - 1) / SCAN_BLK;
    const int nbc = (NR + BROW - 1) / BROW; // 98-row buckets (1021 for NR=100000)

    auto align = [](size_t x) { return (x + 255) & ~(size_t)255; };

    // fast-path layout
    size_t off_ccur    = 0;
    size_t off_scnt    = align(off_ccur + (size_t)nbc * 4);
    size_t off_spill   = align(off_scnt + 4);
    size_t off_wh      = align(off_spill + (size_t)SPILL_CAP * 8);
    size_t off_sortedA = align(off_wh + (size_t)NW * 2);
    size_t needed_full = off_sortedA + (size_t)nbc * BCAP * 8;   // ~22.8 MB

    // tier-2 layout (R2 pipeline)
    size_t t2_counts   = 0;
    size_t t2_tmp      = align(t2_counts + (size_t)NR * 4);
    size_t t2_bsums    = align(t2_tmp    + (size_t)NS * 4);
    size_t t2_rowstart = align(t2_bsums  + (size_t)NB * 4);
    size_t t2_cursor   = align(t2_rowstart + (size_t)NS * 4);
    size_t t2_sorted   = align(t2_cursor + (size_t)NR * 4);
    size_t needed_r2   = t2_sorted + (size_t)nnz * 8;            // ~18 MB

    char* ws = (char*)d_ws;

    if (ws_size >= needed_full && nbc <= NBC_PAD) {
        int*     ccur      = (int*)(ws + off_ccur);
        int*     spill_cnt = (int*)(ws + off_scnt);
        float2*  spill     = (float2*)(ws + off_spill);
        __half2* Wh        = (__half2*)(ws + off_wh);
        float2*  sortedA   = (float2*)(ws + off_sortedA);

        setup_kernel<<<512, 256, 0, stream>>>(W, Wh, ccur, spill_cnt, nbc, NW / 2);
        {
            int grid = (nnz + CH2 - 1) / CH2;
            partition_kernel<<<grid, 512, 0, stream>>>(vals, rows, cols, ccur, sortedA,
                                                       spill_cnt, spill, nnz, nbc);
        }
        fused_sort_compute_kernel<<<nbc, 512, 0, stream>>>(sortedA, ccur, Wh, b, out,
                                                           spill_cnt, spill, NR);
    } else if (ws_size >= needed_r2) {
        int*    counts    = (int*)(ws + t2_counts);
        int*    tmp       = (int*)(ws + t2_tmp);
        int*    bsums     = (int*)(ws + t2_bsums);
        int*    row_start = (int*)(ws + t2_rowstart);
        int*    cursor    = (int*)(ws + t2_cursor);
        float2* sorted    = (float2*)(ws + t2_sorted);

        hipMemsetAsync(counts, 0, (size_t)NR * 4, stream);
        {
            int block = 256, grid = (nnz + block - 1) / block;
            hist_kernel<<<grid, block, 0, stream>>>(rows, counts, nnz);
        }
        scan1_kernel<<<NB, SCAN_BLK, 0, stream>>>(counts, tmp, bsums, NR, NS);
        scan2_kernel<<<1, 64, 0, stream>>>(bsums, NB);
        {
            int block = 256, grid = (NS + block - 1) / block;
            scan3_kernel<<<grid, block, 0, stream>>>(tmp, bsums, row_start, cursor, NR, NS);
        }
        {
            int block = 256, grid = (nnz + block - 1) / block;
            scatter_sort_kernel<<<grid, block, 0, stream>>>(vals, rows, cols, cursor, sorted, nnz);
        }
        {
            int grid = (NR + 3) / 4;
            compute_kernel<<<grid, 256, 0, stream>>>(sorted, row_start, W, b, out, NR);
        }
    } else {
        int total4 = out_size / 4;
        int block = 256;
        int grid = (total4 + block - 1) / block;
        init_bias_kernel<<<grid, block, 0, stream>>>(out, b, total4);
        long long total_threads = (long long)nnz * 32;
        long long g2 = (total_threads + block - 1) / block;
        scatter_atomic_kernel<<<(int)g2, block, 0, stream>>>(vals, rows, cols, W, out, nnz);
    }
}

// Round 3
// 169.633 us; speedup vs baseline: 1.0417x; 1.0417x over previous
//
#include <hip/hip_runtime.h>
#include <hip/hip_fp16.h>

// SparseLinear: out[NR,128] = segment_sum(vals[i] * W[cols[i],:], rows[i]) + b
// R9b: resubmission of R9 (previous bench died of container infra failure).
//  - partition: LDS holds ONLY the inverse permutation (ushort invs[8192], 16KB)
//    + 3x 4KB bucket arrays -> 28KB, 512 thr, 4 blocks/CU = 32 waves/CU.
//    Pass 3 iterates sorted order, re-reads vals/rows/cols (L1/L2-resident
//    32KB windows) -> bucket writes land in consecutive runs (~64B/bucket/chunk).
//  - fused kernel byte-identical to R8 (57.4us, occ 58.6%).

#define UNITS 128
#define SCAN_BLK 1024
#define BROW 98          // rows per bucket (non-pow2 for grid fill)
#define NBC_PAD 1024     // padded bucket slots (actual 1021)
#define BCAP 2528        // fixed bucket capacity (mean 1960, +12.8 sigma)
#define CH2 8192         // partition chunk per block (512 thr * 16)
#define SPILL_CAP 8192

// ---------- setup: cursors + spill counter + W fp32->fp16 ----------

__global__ __launch_bounds__(256) void setup_kernel(
        const float* __restrict__ W, __half2* __restrict__ Wh,
        int* __restrict__ ccur, int* __restrict__ spill_cnt,
        int nbc, int wn2 /* = 8192*128/2 half2 elements */) {
    int t = blockIdx.x * blockDim.x + threadIdx.x;
    if (t < nbc) ccur[t] = t * BCAP;
    if (t == nbc) *spill_cnt = 0;
    int stride = gridDim.x * blockDim.x;
    const float2* W2 = (const float2*)W;
    for (int i = t; i < wn2; i += stride)
        Wh[i] = __float22half2_rn(W2[i]);
}

// ---------- phase A: partition by row/98, rank-sorted coalesced writes ----------

__global__ __launch_bounds__(512, 8) void partition_kernel(
        const float* __restrict__ vals, const int* __restrict__ rows,
        const int* __restrict__ cols, int* __restrict__ ccur,
        float2* __restrict__ sortedA, int* __restrict__ spill_cnt,
        float2* __restrict__ spill, int nnz, int nbc) {
    __shared__ unsigned short invs[CH2];       // 16 KB: sorted-pos -> chunk idx
    __shared__ int hist[NBC_PAD];              //  4 KB: counts -> scatter cursor
    __shared__ int pref[NBC_PAD];              //  4 KB: scan workspace
    __shared__ int gdelta[NBC_PAD];            //  4 KB: global base - local excl

    const int t = threadIdx.x;                 // 512 threads
    const int chunk0 = blockIdx.x * CH2;
    int n = nnz - chunk0;
    if (n > CH2) n = CH2;

    hist[t] = 0; hist[t + 512] = 0;
    __syncthreads();

    // pass 1: histogram; bucket ids cached in registers
    int bk[16];
#pragma unroll
    for (int j = 0; j < 16; ++j) {
        int r = j * 512 + t;
        int bkt = -1;
        if (r < n) {
            bkt = rows[chunk0 + r] / BROW;
            atomicAdd(&hist[bkt], 1);
        }
        bk[j] = bkt;
    }
    __syncthreads();

    // exclusive scan over 1024 slots (2 per thread, Hillis-Steele, 10 steps)
    pref[t] = hist[t]; pref[t + 512] = hist[t + 512];
    __syncthreads();
    for (int off = 1; off < NBC_PAD; off <<= 1) {
        int a0 = (t >= off) ? pref[t - off] : 0;
        int a1 = (t + 512 >= off) ? pref[t + 512 - off] : 0;
        __syncthreads();
        pref[t] += a0; pref[t + 512] += a1;
        __syncthreads();
    }

    // reserve global segments; hist becomes the local-rank cursor (= excl)
#pragma unroll
    for (int u = 0; u < 2; ++u) {
        int s = t + u * 512;
        int c = hist[s];
        int excl = pref[s] - c;
        if (s < nbc) {
            int g = (c > 0) ? atomicAdd(&ccur[s], c) : 0;
            gdelta[s] = g - excl;
        }
        hist[s] = excl;
    }
    __syncthreads();

    // pass 2: build inverse permutation via LDS rank cursor
#pragma unroll
    for (int j = 0; j < 16; ++j) {
        int bkt = bk[j];
        if (bkt >= 0) {
            int pos = atomicAdd(&hist[bkt], 1);
            invs[pos] = (unsigned short)(j * 512 + t);
        }
    }
    __syncthreads();

    // pass 3: iterate sorted order; re-read inputs (L1/L2-resident windows);
    // writes are consecutive runs within each bucket -> coalesced
    for (int s = t; s < n; s += 512) {
        int r = invs[s];
        int i = chunk0 + r;
        int row = rows[i];
        float v = vals[i];
        int col = cols[i];
        int bkt = row / BROW;
        int rowlo = row - bkt * BROW;
        int dest = gdelta[bkt] + s;
        if (dest < (bkt + 1) * BCAP) {
            sortedA[dest] = make_float2(v, __int_as_float(col | (rowlo << 13)));
        } else {
            int sp = atomicAdd(spill_cnt, 1);
            if (sp < SPILL_CAP)
                spill[sp] = make_float2(v, __int_as_float(col | (row << 13)));
        }
    }
}

// ---------- phase B (fused): in-LDS row sort + register accumulate ----------

__global__ __launch_bounds__(512, 8) void fused_sort_compute_kernel(
        const float2* __restrict__ A, const int* __restrict__ ccur,
        const __half2* __restrict__ Wh, const float* __restrict__ b,
        float* __restrict__ out, const int* __restrict__ spill_cnt,
        const float2* __restrict__ spill, int NR) {
    __shared__ float2 st[BCAP + 8];   // ~20.3 KB sorted (val,col) pairs
    __shared__ int cnt_s[128];        // counts -> scatter cursor
    __shared__ int rs[132];           // stable local row starts
    __shared__ int spill_n;
    const int t = threadIdx.x;        // 512 threads = 8 waves
    const int lane = t & 63;
    const int w = t >> 6;
    const int bb = blockIdx.x;
    const int r0 = bb * BROW;
    const int gstart = bb * BCAP;
    int cnt = ccur[bb] - gstart;
    if (cnt > BCAP) cnt = BCAP;       // overflow entries are in the spill list

    const float2 bias = ((const float2*)b)[lane];

    if (t < 128) cnt_s[t] = 0;
    if (t == 0) {
        int sn = *spill_cnt;
        spill_n = (sn > SPILL_CAP) ? SPILL_CAP : sn;
    }
    __syncthreads();

    // pass 1: single global read of the bucket into registers + histogram
    float2 e[5];
#pragma unroll
    for (int j = 0; j < 5; ++j) {
        int k = j * 512 + t;
        if (k < cnt) {
            e[j] = A[gstart + k];
            atomicAdd(&cnt_s[(__float_as_int(e[j].y) >> 13) & 127], 1);
        }
    }
    __syncthreads();

    // exclusive scan over 128 counts
    if (t < 128) rs[t] = cnt_s[t];
    __syncthreads();
    for (int off = 1; off < 128; off <<= 1) {
        int v = (t < 128 && t >= off) ? rs[t - off] : 0;
        __syncthreads();
        if (t < 128) rs[t] += v;
        __syncthreads();
    }
    int excl = (t < 128) ? rs[t] - cnt_s[t] : 0;
    __syncthreads();
    if (t < 128) { rs[t] = excl; cnt_s[t] = excl; }
    if (t == 0) rs[128] = cnt;
    __syncthreads();

    // pass 2: scatter from registers into LDS in exact row order
#pragma unroll
    for (int j = 0; j < 5; ++j) {
        int k = j * 512 + t;
        if (k < cnt) {
            int pk = __float_as_int(e[j].y);
            int p = atomicAdd(&cnt_s[(pk >> 13) & 127], 1);
            st[p] = make_float2(e[j].x, __int_as_float(pk & 8191));
        }
    }
    __syncthreads();

    // compute: wave w -> rows {w, w+8, ...}, register accumulation,
    // fp16 W gathers (L2-resident 2MB table)
    const int sn = spill_n;
    for (int r = w; r < BROW; r += 8) {
        int grow = r0 + r;
        if (grow >= NR) break;        // r increases with wave-uniform stride
        int s = rs[r], ee = rs[r + 1];
        float ax0 = 0.f, ay0 = 0.f, ax1 = 0.f, ay1 = 0.f;
        for (int k = s; k < ee; k += 4) {
            float2 p0 = st[k];
            float2 p1 = st[k + 1];
            float2 p2 = st[k + 2];
            float2 p3 = st[k + 3];
            int c0 = __float_as_int(p0.y) & 8191;
            int c1 = __float_as_int(p1.y) & 8191;
            int c2 = __float_as_int(p2.y) & 8191;
            int c3 = __float_as_int(p3.y) & 8191;
            float v0 = p0.x;
            float v1 = (k + 1 < ee) ? p1.x : 0.f;
            float v2 = (k + 2 < ee) ? p2.x : 0.f;
            float v3 = (k + 3 < ee) ? p3.x : 0.f;
            float2 w0 = __half22float2(Wh[c0 * 64 + lane]);  // 4 independent L2 gathers
            float2 w1 = __half22float2(Wh[c1 * 64 + lane]);
            float2 w2 = __half22float2(Wh[c2 * 64 + lane]);
            float2 w3 = __half22float2(Wh[c3 * 64 + lane]);
            ax0 += v0 * w0.x; ay0 += v0 * w0.y;
            ax1 += v1 * w1.x; ay1 += v1 * w1.y;
            ax0 += v2 * w2.x; ay0 += v2 * w2.y;
            ax1 += v3 * w3.x; ay1 += v3 * w3.y;
        }
        // spill entries (normally sn == 0)
        for (int s2 = 0; s2 < sn; ++s2) {
            float2 es = spill[s2];
            int pk = __float_as_int(es.y);
            if ((pk >> 13) == grow) {
                float2 wv = __half22float2(Wh[(pk & 8191) * 64 + lane]);
                ax0 += es.x * wv.x; ay0 += es.x * wv.y;
            }
        }
        ((float2*)out)[(size_t)grow * 64 + lane] =
            make_float2(ax0 + ax1 + bias.x, ay0 + ay1 + bias.y);
    }
}

// ---------- tier-2 fallback kernels (R2 pipeline, fp32 W) ----------

__global__ void hist_kernel(const int* __restrict__ rows, int* __restrict__ counts, int nnz) {
    int i = blockIdx.x * blockDim.x + threadIdx.x;
    if (i < nnz) atomicAdd(&counts[rows[i]], 1);
}

__global__ void scan1_kernel(const int* __restrict__ counts, int* __restrict__ tmp,
                             int* __restrict__ bsums, int NR, int NS) {
    __shared__ int s[SCAN_BLK];
    int t = threadIdx.x;
    int i = blockIdx.x * SCAN_BLK + t;
    int x = (i < NR) ? counts[i] : 0;
    s[t] = x;
    __syncthreads();
    for (int off = 1; off < SCAN_BLK; off <<= 1) {
        int v = (t >= off) ? s[t - off] : 0;
        __syncthreads();
        s[t] += v;
        __syncthreads();
    }
    if (i < NS) tmp[i] = s[t] - x;
    if (t == SCAN_BLK - 1) bsums[blockIdx.x] = s[SCAN_BLK - 1];
}

__global__ void scan2_kernel(int* __restrict__ bsums, int nb) {
    if (threadIdx.x == 0 && blockIdx.x == 0) {
        int run = 0;
        for (int i = 0; i < nb; ++i) { int c = bsums[i]; bsums[i] = run; run += c; }
    }
}

__global__ void scan3_kernel(const int* __restrict__ tmp, const int* __restrict__ bsums,
                             int* __restrict__ row_start, int* __restrict__ cursor,
                             int NR, int NS) {
    int i = blockIdx.x * blockDim.x + threadIdx.x;
    if (i < NS) {
        int v = tmp[i] + bsums[i >> 10];
        row_start[i] = v;
        if (i < NR) cursor[i] = v;
    }
}

__global__ void scatter_sort_kernel(const float* __restrict__ vals, const int* __restrict__ rows,
                                    const int* __restrict__ cols, int* __restrict__ cursor,
                                    float2* __restrict__ sorted, int nnz) {
    int i = blockIdx.x * blockDim.x + threadIdx.x;
    if (i < nnz) {
        int r = rows[i];
        int p = atomicAdd(&cursor[r], 1);
        sorted[p] = make_float2(vals[i], __int_as_float(cols[i]));
    }
}

__global__ void compute_kernel(const float2* __restrict__ sorted, const int* __restrict__ row_start,
                               const float* __restrict__ W, const float* __restrict__ b,
                               float* __restrict__ out, int NR) {
    int lane = threadIdx.x & 63;
    int wv = threadIdx.x >> 6;
    int row = blockIdx.x * 4 + wv;
    if (row >= NR) return;
    int start = row_start[row];
    int end   = row_start[row + 1];
    const float2* W2 = (const float2*)W;
    float accx0 = 0.f, accy0 = 0.f, accx1 = 0.f, accy1 = 0.f;
    for (int base = start; base < end; base += 64) {
        int m = end - base;
        if (m > 64) m = 64;
        float2 p = make_float2(0.f, __int_as_float(0));
        if (lane < m) p = sorted[base + lane];
        int vi = __float_as_int(p.x);
        int ci = __float_as_int(p.y);
        int rounds = (m + 3) & ~3;
        for (int j = 0; j < rounds; j += 4) {
            float v0 = __int_as_float(__builtin_amdgcn_readlane(vi, j));
            int   c0 = __builtin_amdgcn_readlane(ci, j);
            float v1 = __int_as_float(__builtin_amdgcn_readlane(vi, j + 1));
            int   c1 = __builtin_amdgcn_readlane(ci, j + 1);
            float v2 = __int_as_float(__builtin_amdgcn_readlane(vi, j + 2));
            int   c2 = __builtin_amdgcn_readlane(ci, j + 2);
            float v3 = __int_as_float(__builtin_amdgcn_readlane(vi, j + 3));
            int   c3 = __builtin_amdgcn_readlane(ci, j + 3);
            float2 w0 = W2[c0 * 64 + lane];
            float2 w1 = W2[c1 * 64 + lane];
            float2 w2 = W2[c2 * 64 + lane];
            float2 w3 = W2[c3 * 64 + lane];
            accx0 += v0 * w0.x; accy0 += v0 * w0.y;
            accx1 += v1 * w1.x; accy1 += v1 * w1.y;
            accx0 += v2 * w2.x; accy0 += v2 * w2.y;
            accx1 += v3 * w3.x; accy1 += v3 * w3.y;
        }
    }
    float2 bb = ((const float2*)b)[lane];
    ((float2*)out)[(size_t)row * 64 + lane] =
        make_float2(accx0 + accx1 + bb.x, accy0 + accy1 + bb.y);
}

// ---------- tier-3 fallback (atomic path) ----------

__global__ void init_bias_kernel(float* __restrict__ out, const float* __restrict__ b, int total4) {
    const float4* b4 = (const float4*)b;
    float4* out4 = (float4*)out;
    int stride = gridDim.x * blockDim.x;
    for (int j = blockIdx.x * blockDim.x + threadIdx.x; j < total4; j += stride)
        out4[j] = b4[j & 31];
}

__global__ void scatter_atomic_kernel(const float* __restrict__ vals, const int* __restrict__ rows,
                                      const int* __restrict__ cols, const float* __restrict__ W,
                                      float* __restrict__ out, int nnz) {
    long long idx = (long long)blockIdx.x * blockDim.x + threadIdx.x;
    int i = (int)(idx >> 5);
    int c = (int)(idx & 31);
    if (i >= nnz) return;
    int row = rows[i], col = cols[i];
    float v = vals[i];
    float4 w = ((const float4*)W)[col * 32 + c];
    float* o = out + (size_t)row * UNITS + (c << 2);
    atomicAdd(o + 0, v * w.x);
    atomicAdd(o + 1, v * w.y);
    atomicAdd(o + 2, v * w.z);
    atomicAdd(o + 3, v * w.w);
}

extern "C" void kernel_launch(void* const* d_in, const int* in_sizes, int n_in,
                              void* d_out, int out_size, void* d_ws, size_t ws_size,
                              hipStream_t stream) {
    const float* vals = (const float*)d_in[0];
    const int*   rows = (const int*)d_in[1];
    const int*   cols = (const int*)d_in[2];
    const float* W    = (const float*)d_in[3];
    const float* b    = (const float*)d_in[4];
    float* out = (float*)d_out;

    const int nnz = in_sizes[0];
    const int NW  = in_sizes[3];            // 8192*128
    const int NR  = out_size / UNITS;
    const int NS  = NR + 1;
    const int NB  = (NS + SCAN_BLK - 1) / SCAN_BLK;
    const int nbc = (NR + BROW - 1) / BROW; // 98-row buckets (1021 for NR=100000)

    auto align = [](size_t x) { return (x + 255) & ~(size_t)255; };

    // fast-path layout
    size_t off_ccur    = 0;
    size_t off_scnt    = align(off_ccur + (size_t)nbc * 4);
    size_t off_spill   = align(off_scnt + 4);
    size_t off_wh      = align(off_spill + (size_t)SPILL_CAP * 8);
    size_t off_sortedA = align(off_wh + (size_t)NW * 2);
    size_t needed_full = off_sortedA + (size_t)nbc * BCAP * 8;   // ~22.8 MB

    // tier-2 layout (R2 pipeline)
    size_t t2_counts   = 0;
    size_t t2_tmp      = align(t2_counts + (size_t)NR * 4);
    size_t t2_bsums    = align(t2_tmp    + (size_t)NS * 4);
    size_t t2_rowstart = align(t2_bsums  + (size_t)NB * 4);
    size_t t2_cursor   = align(t2_rowstart + (size_t)NS * 4);
    size_t t2_sorted   = align(t2_cursor + (size_t)NR * 4);
    size_t needed_r2   = t2_sorted + (size_t)nnz * 8;            // ~18 MB

    char* ws = (char*)d_ws;

    if (ws_size >= needed_full && nbc <= NBC_PAD) {
        int*     ccur      = (int*)(ws + off_ccur);
        int*     spill_cnt = (int*)(ws + off_scnt);
        float2*  spill     = (float2*)(ws + off_spill);
        __half2* Wh        = (__half2*)(ws + off_wh);
        float2*  sortedA   = (float2*)(ws + off_sortedA);

        setup_kernel<<<512, 256, 0, stream>>>(W, Wh, ccur, spill_cnt, nbc, NW / 2);
        {
            int grid = (nnz + CH2 - 1) / CH2;
            partition_kernel<<<grid, 512, 0, stream>>>(vals, rows, cols, ccur, sortedA,
                                                       spill_cnt, spill, nnz, nbc);
        }
        fused_sort_compute_kernel<<<nbc, 512, 0, stream>>>(sortedA, ccur, Wh, b, out,
                                                           spill_cnt, spill, NR);
    } else if (ws_size >= needed_r2) {
        int*    counts    = (int*)(ws + t2_counts);
        int*    tmp       = (int*)(ws + t2_tmp);
        int*    bsums     = (int*)(ws + t2_bsums);
        int*    row_start = (int*)(ws + t2_rowstart);
        int*    cursor    = (int*)(ws + t2_cursor);
        float2* sorted    = (float2*)(ws + t2_sorted);

        hipMemsetAsync(counts, 0, (size_t)NR * 4, stream);
        {
            int block = 256, grid = (nnz + block - 1) / block;
            hist_kernel<<<grid, block, 0, stream>>>(rows, counts, nnz);
        }
        scan1_kernel<<<NB, SCAN_BLK, 0, stream>>>(counts, tmp, bsums, NR, NS);
        scan2_kernel<<<1, 64, 0, stream>>>(bsums, NB);
        {
            int block = 256, grid = (NS + block - 1) / block;
            scan3_kernel<<<grid, block, 0, stream>>>(tmp, bsums, row_start, cursor, NR, NS);
        }
        {
            int block = 256, grid = (nnz + block - 1) / block;
            scatter_sort_kernel<<<grid, block, 0, stream>>>(vals, rows, cols, cursor, sorted, nnz);
        }
        {
            int grid = (NR + 3) / 4;
            compute_kernel<<<grid, 256, 0, stream>>>(sorted, row_start, W, b, out, NR);
        }
    } else {
        int total4 = out_size / 4;
        int block = 256;
        int grid = (total4 + block - 1) / block;
        init_bias_kernel<<<grid, block, 0, stream>>>(out, b, total4);
        long long total_threads = (long long)nnz * 32;
        long long g2 = (total_threads + block - 1) / block;
        scatter_atomic_kernel<<<(int)g2, block, 0, stream>>>(vals, rows, cols, W, out, nnz);
    }
}